// Round 7
// baseline (579.548 us; speedup 1.0000x reference)
//
#include <hip/hip_runtime.h>
#include <stdint.h>

typedef unsigned int  uint32;
typedef unsigned short u16;
typedef __attribute__((ext_vector_type(8))) short short8;
typedef __attribute__((ext_vector_type(4))) float f32x4;
typedef __attribute__((ext_vector_type(4))) _Float16 half4;

// ---------- helpers ----------
__device__ __forceinline__ float bits2f(uint32 u){ union{uint32 u; float f;} c; c.u=u; return c.f; }
__device__ __forceinline__ uint32 f2bits(float f){ union{uint32 u; float f;} c; c.f=f; return c.u; }
__device__ __forceinline__ u16 f2b(float f){ uint32 u=f2bits(f); return (u16)((u + 0x7FFFu + ((u>>16)&1u))>>16); }
__device__ __forceinline__ float b2f(u16 h){ return bits2f(((uint32)h)<<16); }
__device__ __forceinline__ u16 f2h(float f){ _Float16 h=(_Float16)f; union{u16 u; _Float16 h;} c; c.h=h; return c.u; }
__device__ __forceinline__ float4 ld4f(const float* p){ return *(const float4*)p; }
#define BLO(u) bits2f((u)<<16)
#define BHI(u) bits2f((u)&0xFFFF0000u)

#define QKS 24
#define GRID 512

struct Params {
  const float* node;
  const float *Wq,*bq,*Wk,*bk,*Wv,*bv,*Ww,*bw,*Wf1,*bf1,*Wf2,*bf2;
  const float *g1,*be1,*g2,*be2;
  float* out;
  u16 *wb, *qb, *kb, *vb, *ab, *xb, *x2b, *hb;
  float* accbuf;        // 512 floats: sum1[128] sq1[128] sum2[128] sq2[128]
  int *cnt, *gen;       // global barrier state (zeroed by memsetAsync each call)
};

union SharedU {
  struct { u16 As[128*72]; u16 Ws[128*72]; } g;                    // 36864 B
  struct { u16 Qs[256*QKS]; u16 Ks[256*QKS]; u16 Vt[16*264]; } a;  // 33024 B
};

// ---------- software grid barrier (all GRID blocks guaranteed co-resident) ----------
__device__ __forceinline__ void gbar(int* cnt, int* gen)
{
  __syncthreads();
  if (threadIdx.x == 0) {
    __threadfence();   // release: make this block's writes device-visible
    const int g = __hip_atomic_load(gen, __ATOMIC_RELAXED, __HIP_MEMORY_SCOPE_AGENT);
    const int a = __hip_atomic_fetch_add(cnt, 1, __ATOMIC_ACQ_REL, __HIP_MEMORY_SCOPE_AGENT);
    if (a == GRID - 1) {
      __hip_atomic_store(cnt, 0, __ATOMIC_RELAXED, __HIP_MEMORY_SCOPE_AGENT);
      __hip_atomic_fetch_add(gen, 1, __ATOMIC_RELEASE, __HIP_MEMORY_SCOPE_AGENT);
    } else {
      while (__hip_atomic_load(gen, __ATOMIC_RELAXED, __HIP_MEMORY_SCOPE_AGENT) == g)
        __builtin_amdgcn_s_sleep(8);
    }
    __threadfence();   // acquire
  }
  __syncthreads();
}

// ---------- weights fp32 -> bf16, one job = 256 float4 ----------
__device__ __forceinline__ void cvt_job(const Params& p, int j, int t)
{
  const int i = j * 256 + t;
  const float4* src;
  if      (i <  4096) src = (const float4*)p.Wq  + i;
  else if (i <  8192) src = (const float4*)p.Wk  + (i-4096);
  else if (i < 12288) src = (const float4*)p.Wv  + (i-8192);
  else if (i < 16384) src = (const float4*)p.Ww  + (i-12288);
  else if (i < 32768) src = (const float4*)p.Wf1 + (i-16384);
  else                src = (const float4*)p.Wf2 + (i-32768);
  float4 v = *src;
  uint2 o;
  o.x = (uint32)f2b(v.x) | ((uint32)f2b(v.y) << 16);
  o.y = (uint32)f2b(v.z) | ((uint32)f2b(v.w) << 16);
  *(uint2*)(p.wb + (size_t)i*4) = o;
}

// ---------- fold raw BN sums into per-channel affine in LDS ----------
__device__ __forceinline__ void load_ab(const float* __restrict__ gacc,
                                        const float* __restrict__ gam,
                                        const float* __restrict__ bet,
                                        float* sA, float* sB, int t)
{
  if (t < 128) {
    const float mean = gacc[t] * (1.f/32768.f);
    const float var  = gacc[128 + t] * (1.f/32768.f) - mean * mean;
    const float rstd = rsqrtf(var + 1e-5f);
    const float Ac = gam[t] * rstd;
    sA[t] = Ac;
    sB[t] = bet[t] - mean * Ac;
  }
  __syncthreads();
}

// ---------- GEMM tile job: 128 x (JT*32), BK=64, 4 waves, 16x16x32 bf16 MFMA ----------
// OMODE: 0 bf16 row-major | 2 f16 [T][M][N][D] (*oscale) | 3 f16 [T][M][D][N]
// RES: 0 none | 1 f32 stride128 | 3 bf16 stride128 * BN affine (sA/sB)
// AF32: A fp32 convert in staging. BNA: BN affine on A channels (K==128, sA/sB).
// STATS: epilogue channel sums -> gacc_out atomics (Nout==128).
template<int OMODE, int RES, bool RELU, bool AF32, bool BNA, bool STATS, int JT>
__device__ __forceinline__ void gemm_tile(
    SharedU* Up, const float* sA, const float* sB, float* pS, float* pQ,
    const void* Ain, const u16* W, const float* bias, const void* res,
    float* gacc_out, void* out, int row0, int col0, int K, int Nout,
    float oscale, int t)
{
  constexpr int WROWS = JT * 32;
  u16* As = Up->g.As;
  u16* Ws = Up->g.Ws;
  const int L = t & 63, w = t >> 6;
  const int wrow = (w >> 1) * 64, wcol = (w & 1) * (JT * 16);
  const int lm = L & 15, lg = L >> 4;

  f32x4 acc[4][JT];
#pragma unroll
  for (int i = 0; i < 4; ++i)
#pragma unroll
    for (int j = 0; j < JT; ++j) acc[i][j] = (f32x4){0.f,0.f,0.f,0.f};

  const int srow = t >> 1, skc = (t & 1) * 32;
  const u16*   Ab = (const u16*)Ain + (size_t)(row0 + srow) * K + skc;
  const float* Af = (const float*)Ain + (size_t)(row0 + srow) * K + skc;
  u16* Asp = As + srow * 72 + skc;
  constexpr int TPR = 256 / WROWS;
  const int wsrow = t / TPR, wskc = (t % TPR) * (64 / TPR);
  const u16* Wp = W + (size_t)(col0 + wsrow) * K + wskc;
  u16* Wsp = Ws + wsrow * 72 + wskc;
  constexpr int NW = (64 / TPR) / 8;

  for (int k0 = 0; k0 < K; k0 += 64) {
    short8 ga[4], gw[NW];
    if constexpr (AF32) {
#pragma unroll
      for (int i = 0; i < 4; ++i) {
        const float4 fa = ld4f(Af + k0 + i*8);
        const float4 fb = ld4f(Af + k0 + i*8 + 4);
        short8 s;
        s[0]=(short)f2b(fa.x); s[1]=(short)f2b(fa.y); s[2]=(short)f2b(fa.z); s[3]=(short)f2b(fa.w);
        s[4]=(short)f2b(fb.x); s[5]=(short)f2b(fb.y); s[6]=(short)f2b(fb.z); s[7]=(short)f2b(fb.w);
        ga[i] = s;
      }
    } else if constexpr (BNA) {
#pragma unroll
      for (int i = 0; i < 4; ++i) {
        const int c = skc + k0 + i*8;   // channel (K == 128)
        const short8 x8 = *(const short8*)(Ab + k0 + i*8);
        const float4 A0 = *(const float4*)&sA[c], A1 = *(const float4*)&sA[c+4];
        const float4 B0 = *(const float4*)&sB[c], B1 = *(const float4*)&sB[c+4];
        short8 s;
        s[0]=(short)f2b(b2f((u16)x8[0])*A0.x+B0.x); s[1]=(short)f2b(b2f((u16)x8[1])*A0.y+B0.y);
        s[2]=(short)f2b(b2f((u16)x8[2])*A0.z+B0.z); s[3]=(short)f2b(b2f((u16)x8[3])*A0.w+B0.w);
        s[4]=(short)f2b(b2f((u16)x8[4])*A1.x+B1.x); s[5]=(short)f2b(b2f((u16)x8[5])*A1.y+B1.y);
        s[6]=(short)f2b(b2f((u16)x8[6])*A1.z+B1.z); s[7]=(short)f2b(b2f((u16)x8[7])*A1.w+B1.w);
        ga[i] = s;
      }
    } else {
#pragma unroll
      for (int i = 0; i < 4; ++i) ga[i] = *(const short8*)(Ab + k0 + i*8);
    }
#pragma unroll
    for (int i = 0; i < NW; ++i) gw[i] = *(const short8*)(Wp + k0 + i*8);
    __syncthreads();   // previous chunk / previous job's LDS fully consumed
#pragma unroll
    for (int i = 0; i < 4; ++i) *(short8*)(Asp + i*8) = ga[i];
#pragma unroll
    for (int i = 0; i < NW; ++i) *(short8*)(Wsp + i*8) = gw[i];
    __syncthreads();
#pragma unroll
    for (int ks = 0; ks < 64; ks += 32) {
      short8 af[4], wf[JT];
#pragma unroll
      for (int i = 0; i < 4; ++i)
        af[i] = *(const short8*)(As + (wrow + i*16 + lm) * 72 + ks + lg*8);
#pragma unroll
      for (int j = 0; j < JT; ++j)
        wf[j] = *(const short8*)(Ws + (wcol + j*16 + lm) * 72 + ks + lg*8);
#pragma unroll
      for (int i = 0; i < 4; ++i)
#pragma unroll
        for (int j = 0; j < JT; ++j)
          acc[i][j] = __builtin_amdgcn_mfma_f32_16x16x32_bf16(af[i], wf[j], acc[i][j], 0, 0, 0);
    }
  }

  float bj[JT];
#pragma unroll
  for (int j = 0; j < JT; ++j) bj[j] = bias[col0 + wcol + j*16 + lm];

  float stS[JT], stQ[JT];
#pragma unroll
  for (int j = 0; j < JT; ++j) { stS[j] = 0.f; stQ[j] = 0.f; }

#pragma unroll
  for (int i = 0; i < 4; ++i) {
    const int rowb = row0 + wrow + i*16 + lg*4;
#pragma unroll
    for (int j = 0; j < JT; ++j) {
      const int col = col0 + wcol + j*16 + lm;
      float ra = 0.f, rb = 0.f;
      if constexpr (RES == 3) { ra = sA[col & 127]; rb = sB[col & 127]; }
      if constexpr (OMODE == 3) {   // f16 [T][M][D][N]
        const int tt = rowb >> 8, n0 = rowb & 255;
        const int mh = col >> 4, d = col & 15;
        uint2 o;
        o.x = (uint32)f2h(acc[i][j][0] + bj[j]) | ((uint32)f2h(acc[i][j][1] + bj[j]) << 16);
        o.y = (uint32)f2h(acc[i][j][2] + bj[j]) | ((uint32)f2h(acc[i][j][3] + bj[j]) << 16);
        *(uint2*)((u16*)out + (((size_t)tt*8 + mh)*16 + d)*256 + n0) = o;
      } else {
#pragma unroll
        for (int r = 0; r < 4; ++r) {
          const int row = rowb + r;
          float v = acc[i][j][r] + bj[j];
          if constexpr (RES == 1) v += ((const float*)res)[(size_t)row*128 + col];
          if constexpr (RES == 3) v += b2f(((const u16*)res)[(size_t)row*128 + col]) * ra + rb;
          if constexpr (RELU) v = fmaxf(v, 0.f);
          if constexpr (STATS) { stS[j] += v; stQ[j] += v*v; }
          if constexpr (OMODE == 2) {
            const int tt = row >> 8, n = row & 255, mh = col >> 4, d = col & 15;
            ((u16*)out)[(((size_t)tt*8 + mh)*256 + n)*16 + d] = f2h(v * oscale);
          } else {
            ((u16*)out)[(size_t)row * Nout + col] = f2b(v);
          }
        }
      }
    }
  }

  if constexpr (STATS) {   // Nout == 128
    __syncthreads();
    if (t < 128) { pS[t] = 0.f; pQ[t] = 0.f; }
    __syncthreads();
#pragma unroll
    for (int j = 0; j < JT; ++j) {
      const int col = col0 + wcol + j*16 + lm;
      atomicAdd(&pS[col], stS[j]);
      atomicAdd(&pQ[col], stQ[j]);
    }
    __syncthreads();
    if (t < 128) {
      atomicAdd(&gacc_out[t],       pS[t]);
      atomicAdd(&gacc_out[128 + t], pQ[t]);
    }
  }
}

// ---------- attention job: one (t,m), 4 waves, f16 16x16x16 MFMA ----------
__device__ __forceinline__ void attn_job(SharedU* Up, const u16* q, const u16* k,
                                         const u16* v, u16* ab, int tm, int t)
{
  u16* Qs = Up->a.Qs; u16* Ks = Up->a.Ks; u16* Vt = Up->a.Vt;
  const int tt = tm >> 3, m = tm & 7;

  const uint4* qg = (const uint4*)(q + (size_t)tm*4096);
  const uint4* kg = (const uint4*)(k + (size_t)tm*4096);
  const uint4* vg = (const uint4*)(v + (size_t)tm*4096);
  __syncthreads();   // previous job's LDS reads done
#pragma unroll
  for (int p = t; p < 512; p += 256) {
    const uint4 a = qg[p], b = kg[p], c = vg[p];
    const int row = p >> 1, h = (p & 1) * 8;
    *(uint4*)(Qs + row*QKS + h) = a;
    *(uint4*)(Ks + row*QKS + h) = b;
    *(uint4*)(Vt + (p >> 5)*264 + (p & 31)*8) = c;
  }
  __syncthreads();

  const int w = t >> 6, L = t & 63, lm = L & 15, quad = L >> 4;

  half4 vf[16];
#pragma unroll
  for (int jt = 0; jt < 16; ++jt)
    vf[jt] = *(const half4*)(Vt + lm*264 + jt*16 + quad*4);

  for (int nt = 0; nt < 4; ++nt) {
    const half4 bq = *(const half4*)(Qs + ((w*4 + nt)*16 + lm)*QKS + quad*4);
    f32x4 s[16];
#pragma unroll
    for (int jt = 0; jt < 16; ++jt) {
      const half4 af = *(const half4*)(Ks + (jt*16 + lm)*QKS + quad*4);
      s[jt] = __builtin_amdgcn_mfma_f32_16x16x16f16(af, bq, (f32x4){0.f,0.f,0.f,0.f}, 0, 0, 0);
    }
    float mx = s[0][0];
#pragma unroll
    for (int jt = 0; jt < 16; ++jt)
#pragma unroll
      for (int r = 0; r < 4; ++r) mx = fmaxf(mx, s[jt][r]);
    mx = fmaxf(mx, __shfl_xor(mx, 16));
    mx = fmaxf(mx, __shfl_xor(mx, 32));
    float ls = 0.f;
#pragma unroll
    for (int jt = 0; jt < 16; ++jt)
#pragma unroll
      for (int r = 0; r < 4; ++r) { const float p = exp2f(s[jt][r] - mx); s[jt][r] = p; ls += p; }
    ls += __shfl_xor(ls, 16);
    ls += __shfl_xor(ls, 32);

    f32x4 oacc = {0.f,0.f,0.f,0.f};
#pragma unroll
    for (int jt = 0; jt < 16; ++jt) {
      half4 pf;
      pf[0] = (_Float16)s[jt][0]; pf[1] = (_Float16)s[jt][1];
      pf[2] = (_Float16)s[jt][2]; pf[3] = (_Float16)s[jt][3];
      oacc = __builtin_amdgcn_mfma_f32_16x16x16f16(pf, vf[jt], oacc, 0, 0, 0);
    }
    const int q0 = w*64 + nt*16 + quad*4;
#pragma unroll
    for (int r = 0; r < 4; ++r) {
      const float lr = __shfl(ls, quad*4 + r);
      ab[((size_t)tt*256 + q0 + r)*128 + m*16 + lm] = f2b(oacc[r] / lr);
    }
  }
}

// ---------- whole layer, persistent kernel, 512 blocks (2/CU co-resident) ----------
__global__ __launch_bounds__(256, 2)
void fused_k(Params p)
{
  __shared__ __align__(16) SharedU U;
  __shared__ __align__(16) float sA[128], sB[128];
  __shared__ float pS[128], pQ[128];
  const int t = threadIdx.x, bid = blockIdx.x;
  const float QSCALE = 0.36067376022224085f;  // 0.25 * log2(e)

  const u16* wqb = p.wb;          const u16* wkb = p.wb + 16384;  const u16* wvb = p.wb + 32768;
  const u16* wwb = p.wb + 49152;  const u16* wf1b = p.wb + 65536; const u16* wf2b = p.wb + 131072;

  // 0: weights fp32 -> bf16
  for (int j = bid; j < 192; j += GRID) cvt_job(p, j, t);
  gbar(p.cnt, p.gen);

  // A: QKV projections (node fp32 converted in staging; f16 perm out)
  for (int j = bid; j < 768; j += GRID) {
    const int x = j & 255, y = j >> 8;
    if (y == 0)
      gemm_tile<2,0,false,true,false,false,4>(&U,sA,sB,pS,pQ, p.node, wqb, p.bq,
          nullptr, nullptr, p.qb, x*128, 0, 128, 128, QSCALE, t);
    else if (y == 1)
      gemm_tile<2,0,false,true,false,false,4>(&U,sA,sB,pS,pQ, p.node, wkb, p.bk,
          nullptr, nullptr, p.kb, x*128, 0, 128, 128, 1.f, t);
    else
      gemm_tile<3,0,false,true,false,false,4>(&U,sA,sB,pS,pQ, p.node, wvb, p.bv,
          nullptr, nullptr, p.vb, x*128, 0, 128, 128, 1.f, t);
  }
  gbar(p.cnt, p.gen);

  // B: attention
  for (int j = bid; j < 1024; j += GRID) attn_job(&U, p.qb, p.kb, p.vb, p.ab, j, t);
  gbar(p.cnt, p.gen);

  // C: out-proj + node residual -> xb, BN1 sums -> accbuf[0..256)
  for (int j = bid; j < 256; j += GRID)
    gemm_tile<0,1,false,false,false,true,4>(&U,sA,sB,pS,pQ, p.ab, wwb, p.bw,
        p.node, p.accbuf, p.xb, j*128, 0, 128, 128, 1.f, t);
  gbar(p.cnt, p.gen);

  // D: FFN1, BN1 affine folded into A staging
  load_ab(p.accbuf, p.g1, p.be1, sA, sB, t);
  for (int j = bid; j < 1024; j += GRID) {
    const int x = j & 255, cy = j >> 8;
    gemm_tile<0,0,true,false,true,false,4>(&U,sA,sB,pS,pQ, p.xb, wf1b, p.bf1,
        nullptr, nullptr, p.hb, x*128, cy*128, 128, 512, 1.f, t);
  }
  gbar(p.cnt, p.gen);

  // E: FFN2 (128x64 tiles) + BN1(xb) residual -> x2b, BN2 sums -> accbuf[256..)
  for (int j = bid; j < 512; j += GRID)
    gemm_tile<0,3,false,false,false,true,2>(&U,sA,sB,pS,pQ, p.hb, wf2b, p.bf2,
        p.xb, p.accbuf + 256, p.x2b, (j >> 1)*128, (j & 1)*64, 512, 128, 1.f, t);
  gbar(p.cnt, p.gen);

  // F: BN2 apply -> fp32 out
  load_ab(p.accbuf + 256, p.g2, p.be2, sA, sB, t);
  const uint32* x2 = (const uint32*)p.x2b;
  for (int j = bid; j < 512; j += GRID) {
#pragma unroll 4
    for (int kk = 0; kk < 16; ++kk) {
      const size_t idx = (size_t)j * 4096 + kk * 256 + t;
      const uint32 u = x2[idx];
      const int c = (int)((idx & 63) * 2);
      float2 o;
      o.x = BLO(u) * sA[c]   + sB[c];
      o.y = BHI(u) * sA[c+1] + sB[c+1];
      ((float2*)p.out)[idx] = o;
    }
  }
}

// ---------- launch ----------
extern "C" void kernel_launch(void* const* d_in, const int* in_sizes, int n_in,
                              void* d_out, int out_size, void* d_ws, size_t ws_size,
                              hipStream_t stream)
{
  (void)in_sizes; (void)n_in; (void)out_size; (void)ws_size;
  char* ws = (char*)d_ws;

  Params P;
  P.node = (const float*)d_in[0];
  P.Wq  = (const float*)d_in[1];  P.bq  = (const float*)d_in[2];
  P.Wk  = (const float*)d_in[3];  P.bk  = (const float*)d_in[4];
  P.Wv  = (const float*)d_in[5];  P.bv  = (const float*)d_in[6];
  P.Ww  = (const float*)d_in[7];  P.bw  = (const float*)d_in[8];
  P.Wf1 = (const float*)d_in[9];  P.bf1 = (const float*)d_in[10];
  P.Wf2 = (const float*)d_in[11]; P.bf2 = (const float*)d_in[12];
  P.g1  = (const float*)d_in[13]; P.be1 = (const float*)d_in[14];
  P.g2  = (const float*)d_in[15]; P.be2 = (const float*)d_in[16];
  P.out = (float*)d_out;

  // workspace (bytes); peak ~51.3 MB
  P.wb  = (u16*)(ws + 0);          // weights bf16 concat (384 KB)
  P.qb  = (u16*)(ws + 524288);     // q f16 [T][M][N][D] (pre-scaled)
  P.kb  = (u16*)(ws + 8912896);    // k f16 [T][M][N][D]
  P.vb  = (u16*)(ws + 17301504);   // v f16 [T][M][D][N]
  P.ab  = (u16*)(ws + 25690112);   // attn out bf16 [T][N][E]
  P.xb  = (u16*)(ws + 34078720);   // x (pre-BN1) bf16
  P.x2b = (u16*)(ws + 42467328);   // x2 (pre-BN2) bf16
  P.accbuf = (float*)(ws + 50855936);
  P.cnt = (int*)(ws + 50855936 + 2048);
  P.gen = (int*)(ws + 50855936 + 2052);
  P.hb  = P.qb;                    // FFN hidden bf16 [32768][512], reuses q/k/v/ab

  // zero BN accumulators + barrier state (graph-capturable async memset)
  hipMemsetAsync(ws + 50855936, 0, 4096, stream);

  fused_k<<<dim3(GRID), dim3(256), 0, stream>>>(P);
}

// Round 8
// 205.710 us; speedup vs baseline: 2.8173x; 2.8173x over previous
//
#include <hip/hip_runtime.h>
#include <stdint.h>

typedef unsigned int  uint32;
typedef unsigned short u16;
typedef __attribute__((ext_vector_type(8))) short short8;
typedef __attribute__((ext_vector_type(4))) float f32x4;
typedef __attribute__((ext_vector_type(4))) _Float16 half4;

// ---------- helpers ----------
__device__ __forceinline__ float bits2f(uint32 u){ union{uint32 u; float f;} c; c.u=u; return c.f; }
__device__ __forceinline__ uint32 f2bits(float f){ union{uint32 u; float f;} c; c.f=f; return c.u; }
__device__ __forceinline__ u16 f2b(float f){ uint32 u=f2bits(f); return (u16)((u + 0x7FFFu + ((u>>16)&1u))>>16); }
__device__ __forceinline__ float b2f(u16 h){ return bits2f(((uint32)h)<<16); }
__device__ __forceinline__ u16 f2h(float f){ _Float16 h=(_Float16)f; union{u16 u; _Float16 h;} c; c.h=h; return c.u; }
__device__ __forceinline__ float4 ld4f(const float* p){ return *(const float4*)p; }
#define BLO(u) bits2f((u)<<16)
#define BHI(u) bits2f((u)&0xFFFF0000u)

#define QKS 24

// ---------- fold raw BN sums into per-channel affine in LDS ----------
__device__ __forceinline__ void load_ab(const float* __restrict__ gacc,
                                        const float* __restrict__ gam,
                                        const float* __restrict__ bet,
                                        float* sA, float* sB, int t)
{
  if (t < 128) {
    const float mean = gacc[t] * (1.f/32768.f);
    const float var  = gacc[128 + t] * (1.f/32768.f) - mean * mean;
    const float rstd = rsqrtf(var + 1e-5f);
    const float Ac = gam[t] * rstd;
    sA[t] = Ac;
    sB[t] = bet[t] - mean * Ac;
  }
  __syncthreads();
}

// ---------- GEMM tile: 128 x (JT*32), BK=64, 4 waves, 16x16x32 bf16 MFMA ----------
// OMODE: 0 bf16 row-major | 2 f16 [T][M][N][D] (*oscale) | 3 f16 [T][M][D][N]
// RES: 0 none | 1 f32 stride128 | 3 bf16 stride128 * BN affine (sA/sB)
// AF32: A fp32 convert in staging. WF32: W fp32 convert in staging.
// BNA: BN affine on A channels (K==128, sA/sB). STATS: channel sums -> gacc atomics.
template<int OMODE, int RES, bool RELU, bool AF32, bool WF32, bool BNA, bool STATS, int JT>
__device__ __forceinline__ void gemm_tile(
    u16* As, u16* Ws, const float* sA, const float* sB, float* pS, float* pQ,
    const void* Ain, const void* W, const float* bias, const void* res,
    float* gacc_out, void* out, int row0, int col0, int K, int Nout,
    float oscale, int t)
{
  constexpr int WROWS = JT * 32;
  const int L = t & 63, w = t >> 6;
  const int wrow = (w >> 1) * 64, wcol = (w & 1) * (JT * 16);
  const int lm = L & 15, lg = L >> 4;

  f32x4 acc[4][JT];
#pragma unroll
  for (int i = 0; i < 4; ++i)
#pragma unroll
    for (int j = 0; j < JT; ++j) acc[i][j] = (f32x4){0.f,0.f,0.f,0.f};

  const int srow = t >> 1, skc = (t & 1) * 32;
  const u16*   Ab = (const u16*)Ain + (size_t)(row0 + srow) * K + skc;
  const float* Af = (const float*)Ain + (size_t)(row0 + srow) * K + skc;
  u16* Asp = As + srow * 72 + skc;
  constexpr int TPR = 256 / WROWS;
  const int wsrow = t / TPR, wskc = (t % TPR) * (64 / TPR);
  const u16*   Wp  = (const u16*)W + (size_t)(col0 + wsrow) * K + wskc;
  const float* Wpf = (const float*)W + (size_t)(col0 + wsrow) * K + wskc;
  u16* Wsp = Ws + wsrow * 72 + wskc;
  constexpr int NW = (64 / TPR) / 8;

  for (int k0 = 0; k0 < K; k0 += 64) {
    short8 ga[4], gw[NW];
    if constexpr (AF32) {
#pragma unroll
      for (int i = 0; i < 4; ++i) {
        const float4 fa = ld4f(Af + k0 + i*8);
        const float4 fb = ld4f(Af + k0 + i*8 + 4);
        short8 s;
        s[0]=(short)f2b(fa.x); s[1]=(short)f2b(fa.y); s[2]=(short)f2b(fa.z); s[3]=(short)f2b(fa.w);
        s[4]=(short)f2b(fb.x); s[5]=(short)f2b(fb.y); s[6]=(short)f2b(fb.z); s[7]=(short)f2b(fb.w);
        ga[i] = s;
      }
    } else if constexpr (BNA) {
#pragma unroll
      for (int i = 0; i < 4; ++i) {
        const int c = skc + k0 + i*8;   // channel (K == 128)
        const short8 x8 = *(const short8*)(Ab + k0 + i*8);
        const float4 A0 = *(const float4*)&sA[c], A1 = *(const float4*)&sA[c+4];
        const float4 B0 = *(const float4*)&sB[c], B1 = *(const float4*)&sB[c+4];
        short8 s;
        s[0]=(short)f2b(b2f((u16)x8[0])*A0.x+B0.x); s[1]=(short)f2b(b2f((u16)x8[1])*A0.y+B0.y);
        s[2]=(short)f2b(b2f((u16)x8[2])*A0.z+B0.z); s[3]=(short)f2b(b2f((u16)x8[3])*A0.w+B0.w);
        s[4]=(short)f2b(b2f((u16)x8[4])*A1.x+B1.x); s[5]=(short)f2b(b2f((u16)x8[5])*A1.y+B1.y);
        s[6]=(short)f2b(b2f((u16)x8[6])*A1.z+B1.z); s[7]=(short)f2b(b2f((u16)x8[7])*A1.w+B1.w);
        ga[i] = s;
      }
    } else {
#pragma unroll
      for (int i = 0; i < 4; ++i) ga[i] = *(const short8*)(Ab + k0 + i*8);
    }
    if constexpr (WF32) {
#pragma unroll
      for (int i = 0; i < NW; ++i) {
        const float4 fa = ld4f(Wpf + k0 + i*8);
        const float4 fb = ld4f(Wpf + k0 + i*8 + 4);
        short8 s;
        s[0]=(short)f2b(fa.x); s[1]=(short)f2b(fa.y); s[2]=(short)f2b(fa.z); s[3]=(short)f2b(fa.w);
        s[4]=(short)f2b(fb.x); s[5]=(short)f2b(fb.y); s[6]=(short)f2b(fb.z); s[7]=(short)f2b(fb.w);
        gw[i] = s;
      }
    } else {
#pragma unroll
      for (int i = 0; i < NW; ++i) gw[i] = *(const short8*)(Wp + k0 + i*8);
    }
    __syncthreads();   // previous chunk fully consumed
#pragma unroll
    for (int i = 0; i < 4; ++i) *(short8*)(Asp + i*8) = ga[i];
#pragma unroll
    for (int i = 0; i < NW; ++i) *(short8*)(Wsp + i*8) = gw[i];
    __syncthreads();
#pragma unroll
    for (int ks = 0; ks < 64; ks += 32) {
      short8 af[4], wf[JT];
#pragma unroll
      for (int i = 0; i < 4; ++i)
        af[i] = *(const short8*)(As + (wrow + i*16 + lm) * 72 + ks + lg*8);
#pragma unroll
      for (int j = 0; j < JT; ++j)
        wf[j] = *(const short8*)(Ws + (wcol + j*16 + lm) * 72 + ks + lg*8);
#pragma unroll
      for (int i = 0; i < 4; ++i)
#pragma unroll
        for (int j = 0; j < JT; ++j)
          acc[i][j] = __builtin_amdgcn_mfma_f32_16x16x32_bf16(af[i], wf[j], acc[i][j], 0, 0, 0);
    }
  }

  float bj[JT];
#pragma unroll
  for (int j = 0; j < JT; ++j) bj[j] = bias[col0 + wcol + j*16 + lm];

  float stS[JT], stQ[JT];
#pragma unroll
  for (int j = 0; j < JT; ++j) { stS[j] = 0.f; stQ[j] = 0.f; }

#pragma unroll
  for (int i = 0; i < 4; ++i) {
    const int rowb = row0 + wrow + i*16 + lg*4;
#pragma unroll
    for (int j = 0; j < JT; ++j) {
      const int col = col0 + wcol + j*16 + lm;
      float ra = 0.f, rb = 0.f;
      if constexpr (RES == 3) { ra = sA[col & 127]; rb = sB[col & 127]; }
      if constexpr (OMODE == 3) {   // f16 [T][M][D][N]
        const int tt = rowb >> 8, n0 = rowb & 255;
        const int mh = col >> 4, d = col & 15;
        uint2 o;
        o.x = (uint32)f2h(acc[i][j][0] + bj[j]) | ((uint32)f2h(acc[i][j][1] + bj[j]) << 16);
        o.y = (uint32)f2h(acc[i][j][2] + bj[j]) | ((uint32)f2h(acc[i][j][3] + bj[j]) << 16);
        *(uint2*)((u16*)out + (((size_t)tt*8 + mh)*16 + d)*256 + n0) = o;
      } else {
#pragma unroll
        for (int r = 0; r < 4; ++r) {
          const int row = rowb + r;
          float v = acc[i][j][r] + bj[j];
          if constexpr (RES == 1) v += ((const float*)res)[(size_t)row*128 + col];
          if constexpr (RES == 3) v += b2f(((const u16*)res)[(size_t)row*128 + col]) * ra + rb;
          if constexpr (RELU) v = fmaxf(v, 0.f);
          if constexpr (STATS) { stS[j] += v; stQ[j] += v*v; }
          if constexpr (OMODE == 2) {
            const int tt = row >> 8, n = row & 255, mh = col >> 4, d = col & 15;
            ((u16*)out)[(((size_t)tt*8 + mh)*256 + n)*16 + d] = f2h(v * oscale);
          } else {
            ((u16*)out)[(size_t)row * Nout + col] = f2b(v);
          }
        }
      }
    }
  }

  if constexpr (STATS) {   // Nout == 128
    __syncthreads();
    if (t < 128) { pS[t] = 0.f; pQ[t] = 0.f; }
    __syncthreads();
#pragma unroll
    for (int j = 0; j < JT; ++j) {
      const int col = col0 + wcol + j*16 + lm;
      atomicAdd(&pS[col], stS[j]);
      atomicAdd(&pQ[col], stQ[j]);
    }
    __syncthreads();
    if (t < 128) {
      atomicAdd(&gacc_out[t],       pS[t]);
      atomicAdd(&gacc_out[128 + t], pQ[t]);
    }
  }
}

// ---------- node 1: QKV projections (W fp32 in staging) + cvt(Ww,Wf1,Wf2) + zero accbuf ----------
__global__ __launch_bounds__(256)
void qkv_k(const float* __restrict__ node,
           const float* __restrict__ Wq, const float* __restrict__ bq,
           const float* __restrict__ Wk, const float* __restrict__ bk,
           const float* __restrict__ Wv, const float* __restrict__ bv,
           const float* __restrict__ Ww, const float* __restrict__ Wf1,
           const float* __restrict__ Wf2,
           u16* __restrict__ qb, u16* __restrict__ kb, u16* __restrict__ vb,
           u16* __restrict__ wb, float* __restrict__ accbuf)
{
  const int bid = blockIdx.x, t = threadIdx.x;
  if (bid < 768) {
    __shared__ u16 As[128*72];
    __shared__ u16 Ws[128*72];
    __shared__ __align__(16) float sA[128], sB[128];
    __shared__ float pS[128], pQ[128];
    const int x = bid & 255, y = bid >> 8;
    const float QSCALE = 0.36067376022224085f;  // 0.25 * log2(e)
    if (y == 0)
      gemm_tile<2,0,false,true,true,false,false,4>(As,Ws,sA,sB,pS,pQ, node, Wq, bq,
          nullptr, nullptr, qb, x*128, 0, 128, 128, QSCALE, t);
    else if (y == 1)
      gemm_tile<2,0,false,true,true,false,false,4>(As,Ws,sA,sB,pS,pQ, node, Wk, bk,
          nullptr, nullptr, kb, x*128, 0, 128, 128, 1.f, t);
    else
      gemm_tile<3,0,false,true,true,false,false,4>(As,Ws,sA,sB,pS,pQ, node, Wv, bv,
          nullptr, nullptr, vb, x*128, 0, 128, 128, 1.f, t);
  } else if (bid < 912) {
    // convert Ww/Wf1/Wf2 fp32 -> bf16 into wb (layout: Ww@49152, Wf1@65536, Wf2@131072 u16)
    const int i = (bid - 768) * 256 + t;   // 0..36863 float4
    const float4* src; u16* dst;
    if      (i <  4096) { src = (const float4*)Ww  + i;         dst = wb +  49152 + (size_t)i*4; }
    else if (i < 20480) { src = (const float4*)Wf1 + (i-4096);  dst = wb +  65536 + (size_t)(i-4096)*4; }
    else                { src = (const float4*)Wf2 + (i-20480); dst = wb + 131072 + (size_t)(i-20480)*4; }
    float4 v = *src;
    uint2 o;
    o.x = (uint32)f2b(v.x) | ((uint32)f2b(v.y) << 16);
    o.y = (uint32)f2b(v.z) | ((uint32)f2b(v.w) << 16);
    *(uint2*)dst = o;
  } else {
    accbuf[t] = 0.f;
    accbuf[256 + t] = 0.f;
  }
}

// ---------- generic GEMM node wrappers ----------
// out-proj: + node residual, BN1 stats
__global__ __launch_bounds__(256)
void oproj_k(const u16* __restrict__ ab, const u16* __restrict__ wwb,
             const float* __restrict__ bw, const float* __restrict__ node,
             float* __restrict__ accbuf, u16* __restrict__ xb)
{
  __shared__ u16 As[128*72];
  __shared__ u16 Ws[128*72];
  __shared__ __align__(16) float sA[128], sB[128];
  __shared__ float pS[128], pQ[128];
  gemm_tile<0,1,false,false,false,false,true,4>(As,Ws,sA,sB,pS,pQ, ab, wwb, bw,
      node, accbuf, xb, blockIdx.x*128, 0, 128, 128, 1.f, threadIdx.x);
}

// FFN1: BN1 affine folded into A staging
__global__ __launch_bounds__(256)
void ffn1_k(const u16* __restrict__ xb, const u16* __restrict__ wf1b,
            const float* __restrict__ bf1, const float* __restrict__ accbuf,
            const float* __restrict__ g1, const float* __restrict__ be1,
            u16* __restrict__ hb)
{
  __shared__ u16 As[128*72];
  __shared__ u16 Ws[128*72];
  __shared__ __align__(16) float sA[128], sB[128];
  __shared__ float pS[128], pQ[128];
  load_ab(accbuf, g1, be1, sA, sB, threadIdx.x);
  gemm_tile<0,0,true,false,false,true,false,4>(As,Ws,sA,sB,pS,pQ, xb, wf1b, bf1,
      nullptr, nullptr, hb, blockIdx.x*128, blockIdx.y*128, 128, 512, 1.f, threadIdx.x);
}

// FFN2 (128x64 tiles) + BN1(xb) residual, BN2 stats
__global__ __launch_bounds__(256)
void ffn2_k(const u16* __restrict__ hb, const u16* __restrict__ wf2b,
            const float* __restrict__ bf2, const u16* __restrict__ xb,
            const float* __restrict__ accbuf, const float* __restrict__ g1,
            const float* __restrict__ be1, float* __restrict__ acc2,
            u16* __restrict__ x2b)
{
  __shared__ u16 As[128*72];
  __shared__ u16 Ws[64*72];
  __shared__ __align__(16) float sA[128], sB[128];
  __shared__ float pS[128], pQ[128];
  load_ab(accbuf, g1, be1, sA, sB, threadIdx.x);
  gemm_tile<0,3,false,false,false,false,true,2>(As,Ws,sA,sB,pS,pQ, hb, wf2b, bf2,
      xb, acc2, x2b, blockIdx.x*128, blockIdx.y*64, 512, 128, 1.f, threadIdx.x);
}

// ---------- attention: 1 block per (t,m), 4 waves, f16 16x16x16 MFMA ----------
__global__ __launch_bounds__(256)
void attn_k(const u16* __restrict__ q, const u16* __restrict__ k,
            const u16* __restrict__ v, u16* __restrict__ ab)
{
  __shared__ __align__(16) u16 Qs[256*QKS];
  __shared__ __align__(16) u16 Ks[256*QKS];
  __shared__ __align__(16) u16 Vt[16*264];
  const int tm = blockIdx.x, tt = tm >> 3, m = tm & 7;
  const int t = threadIdx.x;

  const uint4* qg = (const uint4*)(q + (size_t)tm*4096);
  const uint4* kg = (const uint4*)(k + (size_t)tm*4096);
  const uint4* vg = (const uint4*)(v + (size_t)tm*4096);
#pragma unroll
  for (int p = t; p < 512; p += 256) {
    const uint4 a = qg[p], b = kg[p], c = vg[p];
    const int row = p >> 1, h = (p & 1) * 8;
    *(uint4*)(Qs + row*QKS + h) = a;
    *(uint4*)(Ks + row*QKS + h) = b;
    *(uint4*)(Vt + (p >> 5)*264 + (p & 31)*8) = c;
  }
  __syncthreads();

  const int w = t >> 6, L = t & 63, lm = L & 15, quad = L >> 4;

  half4 vf[16];
#pragma unroll
  for (int jt = 0; jt < 16; ++jt)
    vf[jt] = *(const half4*)(Vt + lm*264 + jt*16 + quad*4);

  for (int nt = 0; nt < 4; ++nt) {
    const half4 bq = *(const half4*)(Qs + ((w*4 + nt)*16 + lm)*QKS + quad*4);
    f32x4 s[16];
#pragma unroll
    for (int jt = 0; jt < 16; ++jt) {
      const half4 af = *(const half4*)(Ks + (jt*16 + lm)*QKS + quad*4);
      s[jt] = __builtin_amdgcn_mfma_f32_16x16x16f16(af, bq, (f32x4){0.f,0.f,0.f,0.f}, 0, 0, 0);
    }
    float mx = s[0][0];
#pragma unroll
    for (int jt = 0; jt < 16; ++jt)
#pragma unroll
      for (int r = 0; r < 4; ++r) mx = fmaxf(mx, s[jt][r]);
    mx = fmaxf(mx, __shfl_xor(mx, 16));
    mx = fmaxf(mx, __shfl_xor(mx, 32));
    float ls = 0.f;
#pragma unroll
    for (int jt = 0; jt < 16; ++jt)
#pragma unroll
      for (int r = 0; r < 4; ++r) { const float p = exp2f(s[jt][r] - mx); s[jt][r] = p; ls += p; }
    ls += __shfl_xor(ls, 16);
    ls += __shfl_xor(ls, 32);

    f32x4 oacc = {0.f,0.f,0.f,0.f};
#pragma unroll
    for (int jt = 0; jt < 16; ++jt) {
      half4 pf;
      pf[0] = (_Float16)s[jt][0]; pf[1] = (_Float16)s[jt][1];
      pf[2] = (_Float16)s[jt][2]; pf[3] = (_Float16)s[jt][3];
      oacc = __builtin_amdgcn_mfma_f32_16x16x16f16(pf, vf[jt], oacc, 0, 0, 0);
    }
    const int q0 = w*64 + nt*16 + quad*4;
#pragma unroll
    for (int r = 0; r < 4; ++r) {
      const float lr = __shfl(ls, quad*4 + r);
      ab[((size_t)tt*256 + q0 + r)*128 + m*16 + lm] = f2b(oacc[r] / lr);
    }
  }
}

// ---------- final: BN2 affine + apply bf16 -> fp32 out (512 blocks) ----------
__global__ __launch_bounds__(256)
void bn_final(const uint32* __restrict__ x2, const float* __restrict__ gacc,
              const float* __restrict__ gam, const float* __restrict__ bet,
              float* __restrict__ out)
{
  __shared__ float sA[128], sB[128];
  const int t = threadIdx.x;
  load_ab(gacc, gam, bet, sA, sB, t);
#pragma unroll 4
  for (int kk = 0; kk < 16; ++kk) {
    const size_t idx = (size_t)blockIdx.x * 4096 + kk * 256 + t;
    const uint32 u = x2[idx];
    const int c = (int)((idx & 63) * 2);
    float2 o;
    o.x = BLO(u) * sA[c]   + sB[c];
    o.y = BHI(u) * sA[c+1] + sB[c+1];
    ((float2*)out)[idx] = o;
  }
}

// ---------- launch: 6 nodes ----------
extern "C" void kernel_launch(void* const* d_in, const int* in_sizes, int n_in,
                              void* d_out, int out_size, void* d_ws, size_t ws_size,
                              hipStream_t stream)
{
  (void)in_sizes; (void)n_in; (void)out_size; (void)ws_size;
  const float* node = (const float*)d_in[0];
  const float* Wq  = (const float*)d_in[1];  const float* bq  = (const float*)d_in[2];
  const float* Wk  = (const float*)d_in[3];  const float* bk  = (const float*)d_in[4];
  const float* Wv  = (const float*)d_in[5];  const float* bv  = (const float*)d_in[6];
  const float* Ww  = (const float*)d_in[7];  const float* bw  = (const float*)d_in[8];
  const float* Wf1 = (const float*)d_in[9];  const float* bf1 = (const float*)d_in[10];
  const float* Wf2 = (const float*)d_in[11]; const float* bf2 = (const float*)d_in[12];
  const float* g1  = (const float*)d_in[13]; const float* be1 = (const float*)d_in[14];
  const float* g2  = (const float*)d_in[15]; const float* be2 = (const float*)d_in[16];
  float* out = (float*)d_out;
  char* ws = (char*)d_ws;

  // workspace (bytes); peak ~51.3 MB
  u16* wb  = (u16*)(ws + 0);          // weights bf16 concat (Ww@49152, Wf1@65536, Wf2@131072 u16)
  u16* qb  = (u16*)(ws + 524288);     // q f16 [T][M][N][D] (pre-scaled)
  u16* kb  = (u16*)(ws + 8912896);    // k f16 [T][M][N][D]
  u16* vb  = (u16*)(ws + 17301504);   // v f16 [T][M][D][N]
  u16* ab  = (u16*)(ws + 25690112);   // attn out bf16 [T][N][E]
  u16* xb  = (u16*)(ws + 34078720);   // x (pre-BN1) bf16
  u16* x2b = (u16*)(ws + 42467328);   // x2 (pre-BN2) bf16
  float* accbuf = (float*)(ws + 50855936);  // 512 floats: sum1,sq1,sum2,sq2
  u16* hb  = qb;                      // FFN hidden bf16 [32768][512], reuses q/k/v/ab

  u16* wwb = wb + 49152;  u16* wf1b = wb + 65536; u16* wf2b = wb + 131072;

  dim3 blk(256);

  // 1. QKV projections + cvt(Ww,Wf1,Wf2) + zero accbuf   (913 blocks)
  qkv_k<<<dim3(913), blk, 0, stream>>>(node, Wq,bq, Wk,bk, Wv,bv, Ww, Wf1, Wf2,
                                       qb, kb, vb, wb, accbuf);
  // 2. attention
  attn_k<<<dim3(1024), blk, 0, stream>>>(qb, kb, vb, ab);
  // 3. out-proj + node residual -> xb, BN1 sums -> accbuf[0..256)
  oproj_k<<<dim3(256), blk, 0, stream>>>(ab, wwb, bw, node, accbuf, xb);
  // 4. FFN1 (BN1 affine in staging)
  ffn1_k<<<dim3(256,4), blk, 0, stream>>>(xb, wf1b, bf1, accbuf, g1, be1, hb);
  // 5. FFN2 + BN1(xb) residual -> x2b, BN2 sums -> accbuf[256..)
  ffn2_k<<<dim3(256,2), blk, 0, stream>>>(hb, wf2b, bf2, xb, accbuf, g1, be1,
                                          accbuf + 256, x2b);
  // 6. BN2 apply -> fp32 out
  bn_final<<<dim3(512), blk, 0, stream>>>((const uint32*)x2b, accbuf + 256, g2, be2, out);
}